// Round 9
// baseline (540.499 us; speedup 1.0000x reference)
//
#include <hip/hip_runtime.h>
#include <hip/hip_cooperative_groups.h>
#include <stdio.h>

namespace cg = cooperative_groups;

// Sizes fixed by the reference
#define H 4
#define B 8192
#define F 64
#define ALPHA 0.2f
#define NB 4096
#define DMIN (-8.0f)
#define DSCALE 256.0f    // NB / 16 over [-8, 8); clamp keeps monotonicity -> exact
#define TSZ 16
#define NTL (B / TSZ)    // 512 tiles per head
#define PELD 132         // PE row: 64 (e^d*hp) + 64 (e^.2d*hp) + 2 scalar prefixes
#define NBLK 512
#define NTHR 256

__device__ __forceinline__ int bucket_of(float x)
{
  int b = (int)((x - DMIN) * DSCALE);   // monotone non-decreasing in x
  return min(max(b, 0), NB - 1);
}

// =========================================================================
// Cooperative mega-kernel: all phases, grid.sync between them.
// 512 blocks x 256 threads, 2 blocks/CU co-resident.
// =========================================================================
__global__ __launch_bounds__(NTHR, 2) void k_mega(
    const float* __restrict__ h, const float* __restrict__ w,
    const float* __restrict__ a_src, const float* __restrict__ a_dst,
    const float* __restrict__ bias,
    float* __restrict__ hp, float* __restrict__ s, float* __restrict__ dd,
    int* __restrict__ ghist, int* __restrict__ bstart, int* __restrict__ gcur,
    float* __restrict__ dsort, int* __restrict__ isort,
    float* __restrict__ ds2, int* __restrict__ js2,
    float* __restrict__ TS, float* __restrict__ totals,
    float* __restrict__ PE, float* __restrict__ out)
{
  cg::grid_group grid = cg::this_grid();
  const int tid = threadIdx.x;
  const int bid = blockIdx.x;
  const int o = tid & 63, wv = tid >> 6;
  const int gw = bid * 4 + wv;             // global wave id 0..2047

  __shared__ float sh[8192];               // 32 KB, reused across phases
  __shared__ int   shi[16];

  // ---- Phase A: hprime (h @ w, s, d) + zero ghist ------------------------
  {
    if (bid >= 128 && bid < 144) {         // 16 blocks zero ghist (16K ints)
      int z = (bid - 128) * NTHR + tid;
#pragma unroll
      for (int t = 0; t < 4; ++t) ghist[z + t * 4096] = 0;
    }
    int head = bid >> 7, row0 = (bid & 127) * 64;
    float* wl = sh;                        // 4096 floats
    float* hl = sh + 4096;                 // 4096 floats
    const float4* wsrc = (const float4*)(w + (size_t)head * F * F);
    const float4* hsrc = (const float4*)(h + (size_t)row0 * F);
    float4* wl4 = (float4*)wl;
    float4* hl4 = (float4*)hl;
    for (int t = tid; t < F * F / 4; t += NTHR) { wl4[t] = wsrc[t]; hl4[t] = hsrc[t]; }
    __syncthreads();
    float as = a_src[head * F + o];
    float ad = a_dst[head * F + o];
    float acc[16];
#pragma unroll
    for (int rg = 0; rg < 16; ++rg) acc[rg] = 0.f;
#pragma unroll 4
    for (int i4 = 0; i4 < F / 4; ++i4) {
      float w0 = wl[(4 * i4 + 0) * F + o];
      float w1 = wl[(4 * i4 + 1) * F + o];
      float w2 = wl[(4 * i4 + 2) * F + o];
      float w3 = wl[(4 * i4 + 3) * F + o];
#pragma unroll
      for (int rg = 0; rg < 16; ++rg) {
        float4 h4 = *((const float4*)(hl + (rg * 4 + wv) * F) + i4);
        acc[rg] = fmaf(h4.x, w0, fmaf(h4.y, w1, fmaf(h4.z, w2, fmaf(h4.w, w3, acc[rg]))));
      }
    }
#pragma unroll
    for (int rg = 0; rg < 16; ++rg) {
      int r = row0 + rg * 4 + wv;
      hp[((size_t)head * B + r) * F + o] = acc[rg];
      float vs = acc[rg] * as, vd = acc[rg] * ad;
#pragma unroll
      for (int off = 32; off; off >>= 1) { vs += __shfl_down(vs, off); vd += __shfl_down(vd, off); }
      if (o == 0) {
        s[(size_t)head * B + r] = vs;
        dd[(size_t)head * B + r] = vd;
      }
    }
  }
  grid.sync();

  // ---- Phase B: distributed histogram -----------------------------------
  {
    int gt = bid * NTHR + tid;
    if (gt < H * B) {
      int head = gt >> 13, i = gt & (B - 1);
      atomicAdd(&ghist[head * NB + bucket_of(dd[(size_t)head * B + i])], 1);
    }
  }
  grid.sync();

  // ---- Phase C: per-head scan of 4096-bucket hist (4 blocks) -------------
  if (bid < H) {
    int head = bid;
    int lane = tid & 63;
    int v[16];
    int base = head * NB + tid * 16;
#pragma unroll
    for (int t = 0; t < 16; ++t) v[t] = ghist[base + t];
    int sum = 0;
#pragma unroll
    for (int t = 0; t < 16; ++t) { sum += v[t]; v[t] = sum; }   // inclusive
    int run = sum;
#pragma unroll
    for (int off = 1; off < 64; off <<= 1) {
      int u = __shfl_up(run, off);
      if (lane >= off) run += u;
    }
    if (lane == 63) shi[wv] = run;
    __syncthreads();
    int woffv = 0;
    for (int j = 0; j < wv; ++j) woffv += shi[j];
    int excl = woffv + run - sum;
    int bb = head * (NB + 1) + tid * 16;
    int gb = head * NB + tid * 16;
#pragma unroll
    for (int t = 0; t < 16; ++t) {
      int e = excl + (t == 0 ? 0 : v[t - 1]);
      bstart[bb + t] = e;
      gcur[gb + t] = e;
    }
    if (tid == NTHR - 1) bstart[head * (NB + 1) + NB] = excl + v[15];  // == B
  }
  grid.sync();

  // ---- Phase D: bucket scatter -------------------------------------------
  {
    int gt = bid * NTHR + tid;
    if (gt < H * B) {
      int head = gt >> 13, i = gt & (B - 1);
      float v = dd[(size_t)head * B + i];
      int b = bucket_of(v);
      int pos = atomicAdd(&gcur[head * NB + b], 1);
      dsort[(size_t)head * B + pos] = v;
      isort[(size_t)head * B + pos] = i;
    }
  }
  grid.sync();

  // ---- Phase E: exact in-bucket rank sort (8 buckets per wave) -----------
  {
    int lane = o;
#pragma unroll
    for (int t = 0; t < 8; ++t) {
      int g = gw * 8 + t;                  // 0..16383
      int head = g >> 12, b = g & (NB - 1);
      int k0 = bstart[head * (NB + 1) + b];
      int k1 = bstart[head * (NB + 1) + b + 1];
      const float* dh = dsort + (size_t)head * B;
      const int*   ih = isort + (size_t)head * B;
      for (int e = k0 + lane; e < k1; e += 64) {
        float dv = dh[e]; int iv = ih[e];
        int rank = 0;
        for (int k = k0; k < k1; ++k) {
          float d2 = dh[k]; int i2 = ih[k];
          rank += (d2 < dv) || (d2 == dv && i2 < iv);
        }
        ds2[(size_t)head * B + k0 + rank] = dv;
        js2[(size_t)head * B + k0 + rank] = iv;
      }
    }
  }
  grid.sync();

  // ---- Phase F: per-tile sums (1 tile per wave); keep hv/e1/e2 in regs ---
  float e1r[TSZ], e2r[TSZ], hvr[TSZ];
  {
    int head = gw >> 9, tile = gw & (NTL - 1);
    int k0 = tile * TSZ;
    const float* dsh = ds2 + (size_t)head * B;
    const int*   jsh = js2 + (size_t)head * B;
    const float* hph = hp + (size_t)head * B * F;
    int jj[TSZ];
#pragma unroll
    for (int j = 0; j < TSZ; ++j) jj[j] = jsh[k0 + j];
#pragma unroll
    for (int j = 0; j < TSZ; ++j) hvr[j] = hph[(size_t)jj[j] * F + o];
#pragma unroll
    for (int j = 0; j < TSZ; ++j) {
      float dv = dsh[k0 + j];
      e1r[j] = expf(dv); e2r[j] = expf(ALPHA * dv);
    }
    float a1 = 0.f, a2 = 0.f, s1 = 0.f, s2 = 0.f;
#pragma unroll
    for (int j = 0; j < TSZ; ++j) {
      a1 = fmaf(e1r[j], hvr[j], a1);
      a2 = fmaf(e2r[j], hvr[j], a2);
      s1 += e1r[j]; s2 += e2r[j];
    }
    float* row = TS + ((size_t)head * NTL + tile) * PELD;
    row[o] = a1; row[64 + o] = a2;
    if (o == 0) { row[128] = s1; row[129] = s2; }
  }
  grid.sync();

  // ---- Phase G: exclusive scan of tile sums (one wave per head-channel) --
  if (gw < H * 130) {
    int head = gw / 130, c = gw - head * 130;
    float* base = TS + (size_t)head * NTL * PELD + c;
    int t0 = o * 8;
    float v[8];
#pragma unroll
    for (int t = 0; t < 8; ++t) v[t] = base[(size_t)(t0 + t) * PELD];
    float sum = 0.f;
#pragma unroll
    for (int t = 0; t < 8; ++t) { sum += v[t]; v[t] = sum; }
    float run = sum;
#pragma unroll
    for (int off = 1; off < 64; off <<= 1) {
      float u = __shfl_up(run, off);
      if (o >= off) run += u;
    }
    float excl = run - sum;
    if (o == 63) totals[head * PELD + c] = run;
#pragma unroll
    for (int t = 0; t < 8; ++t)
      base[(size_t)(t0 + t) * PELD] = excl + (t == 0 ? 0.f : v[t - 1]);
  }
  grid.sync();

  // ---- Phase H: write PE rows (reuse hv/e1/e2 registers from F) ----------
  {
    int head = gw >> 9, tile = gw & (NTL - 1);
    int k0 = tile * TSZ;
    const float* trow = TS + ((size_t)head * NTL + tile) * PELD;
    float a1 = trow[o], a2 = trow[64 + o], s1 = trow[128], s2 = trow[129];
#pragma unroll
    for (int j = 0; j < TSZ; ++j) {
      float* row = PE + ((size_t)head * B + k0 + j) * PELD;
      row[o] = a1; row[64 + o] = a2;
      if (o == 0) { row[128] = s1; row[129] = s2; }
      a1 = fmaf(e1r[j], hvr[j], a1);
      a2 = fmaf(e2r[j], hvr[j], a2);
      s1 += e1r[j]; s2 += e2r[j];
    }
  }
  grid.sync();

  // ---- Phase I: outputs (16 rows per wave) -------------------------------
  {
    int head = gw >> 9, i0 = (gw & (NTL - 1)) * 16;
    const float* dsh = ds2 + (size_t)head * B;
    const int* bsh = bstart + head * (NB + 1);
    float TE1 = totals[head * PELD + o];
    float T1  = totals[head * PELD + 128];
    float bo  = bias[o];
    float s16 = (o < 16) ? s[(size_t)head * B + i0 + o] : 0.f;
#pragma unroll 4
    for (int r = 0; r < 16; ++r) {
      float si = __shfl(s16, r);
      float t = -si;
      int q = bucket_of(t);
      int k = bsh[q], Eq = bsh[q + 1];
      while (k < Eq && dsh[k] < t) ++k;    // wave-uniform short walk
      const float* row = (k < B) ? (PE + ((size_t)head * B + k) * PELD)
                                 : (totals + head * PELD);
      float pe1 = row[o], pe2 = row[64 + o], p1 = row[128], p2 = row[129];
      float e1f = expf(si), e2f = expf(ALPHA * si);
      float denom = e2f * p2 + e1f * (T1 - p1);
      float num   = e2f * pe2 + e1f * (TE1 - pe1);
      out[(size_t)(i0 + r) * (H * F) + head * F + o] = num / denom + bo;
    }
  }
}

// =========================================================================
// Fallback path: proven R8 kernels (74.8 us) in case cooperative launch
// fails (capture-unsupported or co-residency rejection).
// =========================================================================
__global__ __launch_bounds__(256) void k_hprime(
    const float* __restrict__ h, const float* __restrict__ w,
    const float* __restrict__ a_src, const float* __restrict__ a_dst,
    float* __restrict__ hp, float* __restrict__ s, float* __restrict__ d)
{
  int head = blockIdx.y;
  int row0 = blockIdx.x * 64;
  __shared__ float wl[F * F];
  __shared__ float hl[64 * F];
  const float4* wsrc = (const float4*)(w + (size_t)head * F * F);
  const float4* hsrc = (const float4*)(h + (size_t)row0 * F);
  float4* wl4 = (float4*)wl;
  float4* hl4 = (float4*)hl;
  for (int t = threadIdx.x; t < F * F / 4; t += 256) { wl4[t] = wsrc[t]; hl4[t] = hsrc[t]; }
  __syncthreads();
  int o  = threadIdx.x & 63;
  int rb = threadIdx.x >> 6;
  float as = a_src[head * F + o];
  float ad = a_dst[head * F + o];
  float acc[16];
#pragma unroll
  for (int rg = 0; rg < 16; ++rg) acc[rg] = 0.f;
#pragma unroll 4
  for (int i4 = 0; i4 < F / 4; ++i4) {
    float w0 = wl[(4 * i4 + 0) * F + o];
    float w1 = wl[(4 * i4 + 1) * F + o];
    float w2 = wl[(4 * i4 + 2) * F + o];
    float w3 = wl[(4 * i4 + 3) * F + o];
#pragma unroll
    for (int rg = 0; rg < 16; ++rg) {
      float4 h4 = *((const float4*)(hl + (rg * 4 + rb) * F) + i4);
      acc[rg] = fmaf(h4.x, w0, fmaf(h4.y, w1, fmaf(h4.z, w2, fmaf(h4.w, w3, acc[rg]))));
    }
  }
#pragma unroll
  for (int rg = 0; rg < 16; ++rg) {
    int r = row0 + rg * 4 + rb;
    hp[((size_t)head * B + r) * F + o] = acc[rg];
    float vs = acc[rg] * as, vd = acc[rg] * ad;
#pragma unroll
    for (int off = 32; off; off >>= 1) { vs += __shfl_down(vs, off); vd += __shfl_down(vd, off); }
    if (o == 0) {
      s[(size_t)head * B + r] = vs;
      d[(size_t)head * B + r] = vd;
    }
  }
}

__global__ __launch_bounds__(1024) void k_hist_scan(
    const float* __restrict__ d, int* __restrict__ bstart, int* __restrict__ gcur)
{
  int head = blockIdx.x;
  int tid = threadIdx.x;
  __shared__ int hist[NB];
  __shared__ int wtot[16], woff[16];
#pragma unroll
  for (int t = 0; t < NB / 1024; ++t) hist[tid + t * 1024] = 0;
  __syncthreads();
  const float* dh = d + (size_t)head * B;
#pragma unroll
  for (int t = 0; t < B / 1024; ++t)
    atomicAdd(&hist[bucket_of(dh[tid + t * 1024])], 1);
  __syncthreads();
  int h0 = hist[4 * tid], h1 = hist[4 * tid + 1], h2 = hist[4 * tid + 2], h3 = hist[4 * tid + 3];
  int sum = h0 + h1 + h2 + h3;
  int lane = tid & 63, wid = tid >> 6;
  int run = sum;
#pragma unroll
  for (int off = 1; off < 64; off <<= 1) {
    int v = __shfl_up(run, off);
    if (lane >= off) run += v;
  }
  if (lane == 63) wtot[wid] = run;
  __syncthreads();
  if (tid < 16) {
    int off = 0;
    for (int j = 0; j < tid; ++j) off += wtot[j];
    woff[tid] = off;
  }
  __syncthreads();
  int excl = woff[wid] + run - sum;
  int base = head * (NB + 1) + 4 * tid;
  int gbase = head * NB + 4 * tid;
  int e0 = excl, e1 = e0 + h0, e2 = e1 + h1, e3 = e2 + h2;
  bstart[base] = e0; bstart[base + 1] = e1; bstart[base + 2] = e2; bstart[base + 3] = e3;
  gcur[gbase] = e0; gcur[gbase + 1] = e1; gcur[gbase + 2] = e2; gcur[gbase + 3] = e3;
  if (tid == 1023) bstart[head * (NB + 1) + NB] = e3 + h3;
}

__global__ __launch_bounds__(512) void k_scatter(
    const float* __restrict__ d, int* __restrict__ gcur,
    float* __restrict__ ds, int* __restrict__ is)
{
  int head = blockIdx.y;
  int i = blockIdx.x * 512 + threadIdx.x;
  float v = d[(size_t)head * B + i];
  int b = bucket_of(v);
  int pos = atomicAdd(&gcur[head * NB + b], 1);
  ds[(size_t)head * B + pos] = v;
  is[(size_t)head * B + pos] = i;
}

__global__ __launch_bounds__(256) void k_sort(
    const float* __restrict__ dsort, const int* __restrict__ isort,
    const int* __restrict__ bstart, float* __restrict__ ds2, int* __restrict__ js2)
{
  int head = blockIdx.y;
  int b = blockIdx.x * 4 + (threadIdx.x >> 6);
  int lane = threadIdx.x & 63;
  int k0 = bstart[head * (NB + 1) + b];
  int k1 = bstart[head * (NB + 1) + b + 1];
  const float* dh = dsort + (size_t)head * B;
  const int*   ih = isort + (size_t)head * B;
  for (int e = k0 + lane; e < k1; e += 64) {
    float dv = dh[e]; int iv = ih[e];
    int rank = 0;
    for (int k = k0; k < k1; ++k) {
      float d2 = dh[k]; int i2 = ih[k];
      rank += (d2 < dv) || (d2 == dv && i2 < iv);
    }
    ds2[(size_t)head * B + k0 + rank] = dv;
    js2[(size_t)head * B + k0 + rank] = iv;
  }
}

__global__ __launch_bounds__(256) void k_peA(
    const float* __restrict__ ds2, const int* __restrict__ js2,
    const float* __restrict__ hp, float* __restrict__ TS)
{
  int head = blockIdx.y;
  int tile = blockIdx.x * 4 + (threadIdx.x >> 6);
  int o = threadIdx.x & 63;
  int k0 = tile * TSZ;
  const float* dsh = ds2 + (size_t)head * B;
  const int*   jsh = js2 + (size_t)head * B;
  const float* hph = hp + (size_t)head * B * F;
  float e1[TSZ], e2[TSZ], hv[TSZ];
  int jj[TSZ];
#pragma unroll
  for (int j = 0; j < TSZ; ++j) jj[j] = jsh[k0 + j];
#pragma unroll
  for (int j = 0; j < TSZ; ++j) hv[j] = hph[(size_t)jj[j] * F + o];
#pragma unroll
  for (int j = 0; j < TSZ; ++j) {
    float dv = dsh[k0 + j];
    e1[j] = expf(dv); e2[j] = expf(ALPHA * dv);
  }
  float a1 = 0.f, a2 = 0.f, s1 = 0.f, s2 = 0.f;
#pragma unroll
  for (int j = 0; j < TSZ; ++j) {
    a1 = fmaf(e1[j], hv[j], a1);
    a2 = fmaf(e2[j], hv[j], a2);
    s1 += e1[j]; s2 += e2[j];
  }
  float* row = TS + ((size_t)head * NTL + tile) * PELD;
  row[o] = a1; row[64 + o] = a2;
  if (o == 0) { row[128] = s1; row[129] = s2; }
}

__global__ __launch_bounds__(64) void k_peB(
    float* __restrict__ TS, float* __restrict__ totals)
{
  int head = blockIdx.y;
  int c = blockIdx.x;
  int lane = threadIdx.x;
  float* base = TS + (size_t)head * NTL * PELD + c;
  int t0 = lane * 8;
  float v[8];
#pragma unroll
  for (int t = 0; t < 8; ++t) v[t] = base[(size_t)(t0 + t) * PELD];
  float sum = 0.f;
#pragma unroll
  for (int t = 0; t < 8; ++t) { sum += v[t]; v[t] = sum; }
  float run = sum;
#pragma unroll
  for (int off = 1; off < 64; off <<= 1) {
    float u = __shfl_up(run, off);
    if (lane >= off) run += u;
  }
  float excl = run - sum;
  if (lane == 63) totals[head * PELD + c] = run;
#pragma unroll
  for (int t = 0; t < 8; ++t)
    base[(size_t)(t0 + t) * PELD] = excl + (t == 0 ? 0.f : v[t - 1]);
}

__global__ __launch_bounds__(256) void k_peC(
    const float* __restrict__ ds2, const int* __restrict__ js2,
    const float* __restrict__ hp, const float* __restrict__ TS,
    float* __restrict__ PE)
{
  int head = blockIdx.y;
  int tile = blockIdx.x * 4 + (threadIdx.x >> 6);
  int o = threadIdx.x & 63;
  int k0 = tile * TSZ;
  const float* dsh = ds2 + (size_t)head * B;
  const int*   jsh = js2 + (size_t)head * B;
  const float* hph = hp + (size_t)head * B * F;
  float e1[TSZ], e2[TSZ], hv[TSZ];
  int jj[TSZ];
#pragma unroll
  for (int j = 0; j < TSZ; ++j) jj[j] = jsh[k0 + j];
#pragma unroll
  for (int j = 0; j < TSZ; ++j) hv[j] = hph[(size_t)jj[j] * F + o];
#pragma unroll
  for (int j = 0; j < TSZ; ++j) {
    float dv = dsh[k0 + j];
    e1[j] = expf(dv); e2[j] = expf(ALPHA * dv);
  }
  const float* trow = TS + ((size_t)head * NTL + tile) * PELD;
  float a1 = trow[o], a2 = trow[64 + o], s1 = trow[128], s2 = trow[129];
#pragma unroll
  for (int j = 0; j < TSZ; ++j) {
    float* row = PE + ((size_t)head * B + k0 + j) * PELD;
    row[o] = a1; row[64 + o] = a2;
    if (o == 0) { row[128] = s1; row[129] = s2; }
    a1 = fmaf(e1[j], hv[j], a1);
    a2 = fmaf(e2[j], hv[j], a2);
    s1 += e1[j]; s2 += e2[j];
  }
}

__global__ __launch_bounds__(256) void k_out(
    const float* __restrict__ s, const float* __restrict__ ds2,
    const float* __restrict__ PE, const float* __restrict__ totals,
    const int* __restrict__ bstart, const float* __restrict__ bias,
    float* __restrict__ out)
{
  int head = blockIdx.y;
  int i = blockIdx.x * 4 + (threadIdx.x >> 6);
  int o = threadIdx.x & 63;
  float si = s[(size_t)head * B + i];
  float t = -si;
  int q = bucket_of(t);
  int k  = bstart[head * (NB + 1) + q];
  int Eq = bstart[head * (NB + 1) + q + 1];
  const float* dsh = ds2 + (size_t)head * B;
  while (k < Eq && dsh[k] < t) ++k;
  const float* row = (k < B) ? (PE + ((size_t)head * B + k) * PELD)
                             : (totals + head * PELD);
  float pe1 = row[o], pe2 = row[64 + o], p1 = row[128], p2 = row[129];
  float TE1 = totals[head * PELD + o];
  float T1  = totals[head * PELD + 128];
  float e1f = expf(si), e2f = expf(ALPHA * si);
  float denom = e2f * p2 + e1f * (T1 - p1);
  float num   = e2f * pe2 + e1f * (TE1 - pe1);
  out[(size_t)i * (H * F) + head * F + o] = num / denom + bias[o];
}

// =========================================================================
extern "C" void kernel_launch(void* const* d_in, const int* in_sizes, int n_in,
                              void* d_out, int out_size, void* d_ws, size_t ws_size,
                              hipStream_t stream)
{
  const float* h     = (const float*)d_in[0];
  const float* w     = (const float*)d_in[1];
  const float* a_src = (const float*)d_in[2];
  const float* a_dst = (const float*)d_in[3];
  const float* bias  = (const float*)d_in[4];
  float* out = (float*)d_out;

  float* p = (float*)d_ws;
  float* hp     = p; p += (size_t)H * B * F;        // 8.4 MB
  float* s      = p; p += H * B;
  float* dd     = p; p += H * B;
  float* dsort  = p; p += H * B;
  int*   isort  = (int*)p; p += H * B;
  float* ds2    = p; p += H * B;
  int*   js2    = (int*)p; p += H * B;
  float* PE     = p; p += (size_t)H * B * PELD;     // 17.3 MB
  float* TS     = p; p += (size_t)H * NTL * PELD;   // 1.1 MB
  float* totals = p; p += H * PELD;
  int* ghist    = (int*)p; p += H * NB;
  int* bstart   = (int*)p; p += H * (NB + 1);
  int* gcur     = (int*)p; p += H * NB;

  size_t need = (size_t)((char*)p - (char*)d_ws);
  if (ws_size < need) {
    fprintf(stderr, "kernel_launch: ws_size %zu < needed %zu\n", ws_size, need);
    return;
  }

  // ---- Preferred path: single cooperative mega-kernel --------------------
  void* args[] = {
    (void*)&h, (void*)&w, (void*)&a_src, (void*)&a_dst, (void*)&bias,
    (void*)&hp, (void*)&s, (void*)&dd,
    (void*)&ghist, (void*)&bstart, (void*)&gcur,
    (void*)&dsort, (void*)&isort, (void*)&ds2, (void*)&js2,
    (void*)&TS, (void*)&totals, (void*)&PE, (void*)&out
  };
  hipError_t err = hipLaunchCooperativeKernel(
      (const void*)k_mega, dim3(NBLK), dim3(NTHR), args, 0, stream);
  if (err == hipSuccess) return;

  // ---- Fallback: proven 8-kernel pipeline (deterministic either way) -----
  k_hprime<<<dim3(B / 64, H), 256, 0, stream>>>(h, w, a_src, a_dst, hp, s, dd);
  k_hist_scan<<<H, 1024, 0, stream>>>(dd, bstart, gcur);
  k_scatter<<<dim3(B / 512, H), 512, 0, stream>>>(dd, gcur, dsort, isort);
  k_sort<<<dim3(NB / 4, H), 256, 0, stream>>>(dsort, isort, bstart, ds2, js2);
  k_peA<<<dim3(NTL / 4, H), 256, 0, stream>>>(ds2, js2, hp, TS);
  k_peB<<<dim3(130, H), 64, 0, stream>>>(TS, totals);
  k_peC<<<dim3(NTL / 4, H), 256, 0, stream>>>(ds2, js2, hp, TS, PE);
  k_out<<<dim3(B / 4, H), 256, 0, stream>>>(s, ds2, PE, totals, bstart, bias, out);
}

// Round 10
// 75.605 us; speedup vs baseline: 7.1490x; 7.1490x over previous
//
#include <hip/hip_runtime.h>
#include <stdio.h>

// Sizes fixed by the reference
#define H 4
#define B 8192
#define M2 (2 * B)       // merged stream: B queries (t=-s) + B events (d)
#define F 64
#define ALPHA 0.2f
#define NB 4096
#define DMIN (-8.0f)
#define DSCALE 256.0f    // NB / 16 over [-8, 8); clamp keeps monotonicity -> exact
#define TSZ 16
#define NTL2 (M2 / TSZ)  // 1024 tiles per head
#define PELD 132         // row: 64 (e^d*hp) + 64 (e^.2d*hp) + 2 scalar prefixes

__device__ __forceinline__ int bucket_of(float x)
{
  int b = (int)((x - DMIN) * DSCALE);   // monotone non-decreasing in x
  return min(max(b, 0), NB - 1);
}

// -------------------------------------------------------------------------
// K1: h_prime = h @ w per head; s = hp.a_src, d = hp.a_dst. (R8-proven)
__global__ __launch_bounds__(256) void k_hprime(
    const float* __restrict__ h, const float* __restrict__ w,
    const float* __restrict__ a_src, const float* __restrict__ a_dst,
    float* __restrict__ hp, float* __restrict__ s, float* __restrict__ d)
{
  int head = blockIdx.y;
  int row0 = blockIdx.x * 64;
  __shared__ float wl[F * F];
  __shared__ float hl[64 * F];
  const float4* wsrc = (const float4*)(w + (size_t)head * F * F);
  const float4* hsrc = (const float4*)(h + (size_t)row0 * F);
  float4* wl4 = (float4*)wl;
  float4* hl4 = (float4*)hl;
  for (int t = threadIdx.x; t < F * F / 4; t += 256) { wl4[t] = wsrc[t]; hl4[t] = hsrc[t]; }
  __syncthreads();
  int o  = threadIdx.x & 63;
  int rb = threadIdx.x >> 6;
  float as = a_src[head * F + o];
  float ad = a_dst[head * F + o];
  float acc[16];
#pragma unroll
  for (int rg = 0; rg < 16; ++rg) acc[rg] = 0.f;
#pragma unroll 4
  for (int i4 = 0; i4 < F / 4; ++i4) {
    float w0 = wl[(4 * i4 + 0) * F + o];
    float w1 = wl[(4 * i4 + 1) * F + o];
    float w2 = wl[(4 * i4 + 2) * F + o];
    float w3 = wl[(4 * i4 + 3) * F + o];
#pragma unroll
    for (int rg = 0; rg < 16; ++rg) {
      float4 h4 = *((const float4*)(hl + (rg * 4 + rb) * F) + i4);
      acc[rg] = fmaf(h4.x, w0, fmaf(h4.y, w1, fmaf(h4.z, w2, fmaf(h4.w, w3, acc[rg]))));
    }
  }
#pragma unroll
  for (int rg = 0; rg < 16; ++rg) {
    int r = row0 + rg * 4 + rb;
    hp[((size_t)head * B + r) * F + o] = acc[rg];
    float vs = acc[rg] * as, vd = acc[rg] * ad;
#pragma unroll
    for (int off = 32; off; off >>= 1) { vs += __shfl_down(vs, off); vd += __shfl_down(vd, off); }
    if (o == 0) {
      s[(size_t)head * B + r] = vs;
      d[(size_t)head * B + r] = vd;
    }
  }
}

// -------------------------------------------------------------------------
// K2: per head (1 block of 1024): LDS histogram over the MERGED stream
// (queries -s and events d) -> exclusive scan -> bstart + scatter cursors.
__global__ __launch_bounds__(1024) void k_hist_scan(
    const float* __restrict__ s, const float* __restrict__ d,
    int* __restrict__ bstart, int* __restrict__ gcur)
{
  int head = blockIdx.x;
  int tid = threadIdx.x;
  __shared__ int hist[NB];
  __shared__ int wtot[16], woff[16];
#pragma unroll
  for (int t = 0; t < NB / 1024; ++t) hist[tid + t * 1024] = 0;
  __syncthreads();
  const float* sh = s + (size_t)head * B;
  const float* dh = d + (size_t)head * B;
#pragma unroll
  for (int t = 0; t < B / 1024; ++t)
    atomicAdd(&hist[bucket_of(-sh[tid + t * 1024])], 1);
#pragma unroll
  for (int t = 0; t < B / 1024; ++t)
    atomicAdd(&hist[bucket_of(dh[tid + t * 1024])], 1);
  __syncthreads();
  int h0 = hist[4 * tid], h1 = hist[4 * tid + 1], h2 = hist[4 * tid + 2], h3 = hist[4 * tid + 3];
  int sum = h0 + h1 + h2 + h3;
  int lane = tid & 63, wid = tid >> 6;
  int run = sum;
#pragma unroll
  for (int off = 1; off < 64; off <<= 1) {
    int v = __shfl_up(run, off);
    if (lane >= off) run += v;
  }
  if (lane == 63) wtot[wid] = run;
  __syncthreads();
  if (tid < 16) {
    int off = 0;
    for (int j = 0; j < tid; ++j) off += wtot[j];
    woff[tid] = off;
  }
  __syncthreads();
  int excl = woff[wid] + run - sum;
  int base = head * (NB + 1) + 4 * tid;
  int gbase = head * NB + 4 * tid;
  int e0 = excl, e1 = e0 + h0, e2 = e1 + h1, e3 = e2 + h2;
  bstart[base] = e0; bstart[base + 1] = e1; bstart[base + 2] = e2; bstart[base + 3] = e3;
  gcur[gbase] = e0; gcur[gbase + 1] = e1; gcur[gbase + 2] = e2; gcur[gbase + 3] = e3;
  if (tid == 1023) bstart[head * (NB + 1) + NB] = e3 + h3;   // == M2
}

// -------------------------------------------------------------------------
// K3: bucket scatter of the merged stream. id g: [0,B) query i (v=-s_i),
// [B,2B) event j=g-B (v=d_j). Order within bucket arbitrary; k_sort fixes it.
__global__ __launch_bounds__(512) void k_scatter(
    const float* __restrict__ s, const float* __restrict__ d, int* __restrict__ gcur,
    float* __restrict__ vsort, int* __restrict__ gsort)
{
  int head = blockIdx.y;
  int g = blockIdx.x * 512 + threadIdx.x;     // 0..M2-1
  float v = (g < B) ? -s[(size_t)head * B + g] : d[(size_t)head * B + (g - B)];
  int b = bucket_of(v);
  int pos = atomicAdd(&gcur[head * NB + b], 1);
  vsort[(size_t)head * M2 + pos] = v;
  gsort[(size_t)head * M2 + pos] = g;
}

// -------------------------------------------------------------------------
// K4: exact rank sort within each bucket. Strict total order (v, g):
// at equal v the query (g<B) precedes the event (g>=B) -> prefix at a query
// excludes events with d == t, matching the old `d < t` rule exactly.
__global__ __launch_bounds__(256) void k_sort(
    const float* __restrict__ vsort, const int* __restrict__ gsort,
    const int* __restrict__ bstart, float* __restrict__ vs2, int* __restrict__ gs2)
{
  int head = blockIdx.y;
  int b = blockIdx.x * 4 + (threadIdx.x >> 6);
  int lane = threadIdx.x & 63;
  int k0 = bstart[head * (NB + 1) + b];
  int k1 = bstart[head * (NB + 1) + b + 1];
  const float* vh = vsort + (size_t)head * M2;
  const int*   gh = gsort + (size_t)head * M2;
  for (int e = k0 + lane; e < k1; e += 64) {
    float vv = vh[e]; int gv = gh[e];
    int rank = 0;
    for (int k = k0; k < k1; ++k) {        // wave-uniform broadcast loads
      float v2 = vh[k]; int g2 = gh[k];
      rank += (v2 < vv) || (v2 == vv && g2 < gv);
    }
    vs2[(size_t)head * M2 + k0 + rank] = vv;
    gs2[(size_t)head * M2 + k0 + rank] = gv;
  }
}

// -------------------------------------------------------------------------
// K5a: per-tile sums over the merged order; queries contribute zero.
__global__ __launch_bounds__(256) void k_peA(
    const float* __restrict__ vs2, const int* __restrict__ gs2,
    const float* __restrict__ hp, float* __restrict__ TS)
{
  int head = blockIdx.y;
  int tile = blockIdx.x * 4 + (threadIdx.x >> 6);
  int o = threadIdx.x & 63;
  int k0 = tile * TSZ;
  const float* vsh = vs2 + (size_t)head * M2;
  const int*   gsh = gs2 + (size_t)head * M2;
  const float* hph = hp + (size_t)head * B * F;
  float vv[TSZ]; int gg[TSZ];
#pragma unroll
  for (int j = 0; j < TSZ; ++j) { vv[j] = vsh[k0 + j]; gg[j] = gsh[k0 + j]; }
  float hv[TSZ], e1[TSZ], e2[TSZ];
#pragma unroll
  for (int j = 0; j < TSZ; ++j)
    hv[j] = (gg[j] >= B) ? hph[(size_t)(gg[j] - B) * F + o] : 0.f;
#pragma unroll
  for (int j = 0; j < TSZ; ++j) {
    e1[j] = (gg[j] >= B) ? expf(vv[j]) : 0.f;
    e2[j] = (gg[j] >= B) ? expf(ALPHA * vv[j]) : 0.f;
  }
  float a1 = 0.f, a2 = 0.f, s1 = 0.f, s2 = 0.f;
#pragma unroll
  for (int j = 0; j < TSZ; ++j) {
    a1 = fmaf(e1[j], hv[j], a1);
    a2 = fmaf(e2[j], hv[j], a2);
    s1 += e1[j]; s2 += e2[j];
  }
  float* row = TS + ((size_t)head * NTL2 + tile) * PELD;
  row[o] = a1; row[64 + o] = a2;
  if (o == 0) { row[128] = s1; row[129] = s2; }
}

// K5b: exclusive scan of 1024 tile sums, one wave per (head, channel).
// Lane owns 16 consecutive tiles in registers.
__global__ __launch_bounds__(64) void k_peB(
    float* __restrict__ TS, float* __restrict__ totals)
{
  int head = blockIdx.y;
  int c = blockIdx.x;       // 0..129
  int lane = threadIdx.x;
  float* base = TS + (size_t)head * NTL2 * PELD + c;
  int t0 = lane * 16;
  float v[16];
#pragma unroll
  for (int t = 0; t < 16; ++t) v[t] = base[(size_t)(t0 + t) * PELD];
  float sum = 0.f;
#pragma unroll
  for (int t = 0; t < 16; ++t) { sum += v[t]; v[t] = sum; }  // inclusive chunk prefix
  float run = sum;
#pragma unroll
  for (int off = 1; off < 64; off <<= 1) {
    float u = __shfl_up(run, off);
    if (lane >= off) run += u;
  }
  float excl = run - sum;
  if (lane == 63) totals[head * PELD + c] = run;
#pragma unroll
  for (int t = 0; t < 16; ++t)
    base[(size_t)(t0 + t) * PELD] = excl + (t == 0 ? 0.f : v[t - 1]);
}

// K5c: replay tiles with running prefix; EMIT OUTPUT at each query element.
// The running prefix at a query is exactly the old PE[pos(i)] row.
__global__ __launch_bounds__(256) void k_peC_out(
    const float* __restrict__ vs2, const int* __restrict__ gs2,
    const float* __restrict__ hp, const float* __restrict__ TS,
    const float* __restrict__ totals, const float* __restrict__ bias,
    float* __restrict__ out)
{
  int head = blockIdx.y;
  int tile = blockIdx.x * 4 + (threadIdx.x >> 6);
  int o = threadIdx.x & 63;
  int k0 = tile * TSZ;
  const float* vsh = vs2 + (size_t)head * M2;
  const int*   gsh = gs2 + (size_t)head * M2;
  const float* hph = hp + (size_t)head * B * F;
  float vv[TSZ]; int gg[TSZ];
#pragma unroll
  for (int j = 0; j < TSZ; ++j) { vv[j] = vsh[k0 + j]; gg[j] = gsh[k0 + j]; }
  float hv[TSZ], e1[TSZ], e2[TSZ];
#pragma unroll
  for (int j = 0; j < TSZ; ++j)
    hv[j] = (gg[j] >= B) ? hph[(size_t)(gg[j] - B) * F + o] : 0.f;
#pragma unroll
  for (int j = 0; j < TSZ; ++j) {
    e1[j] = (gg[j] >= B) ? expf(vv[j]) : 0.f;
    e2[j] = (gg[j] >= B) ? expf(ALPHA * vv[j]) : 0.f;
  }
  const float* trow = TS + ((size_t)head * NTL2 + tile) * PELD;
  float a1 = trow[o], a2 = trow[64 + o], s1 = trow[128], s2 = trow[129];
  float TE1 = totals[head * PELD + o];
  float T1  = totals[head * PELD + 128];
  float bo  = bias[o];
#pragma unroll
  for (int j = 0; j < TSZ; ++j) {
    if (gg[j] < B) {                       // query: emit output row (wave-uniform)
      int i = gg[j];
      float si = -vv[j];
      float e1f = expf(si), e2f = expf(ALPHA * si);
      float denom = e2f * s2 + e1f * (T1 - s1);
      float num   = e2f * a2 + e1f * (TE1 - a1);
      out[(size_t)i * (H * F) + head * F + o] = num / denom + bo;
    } else {                               // event: accumulate prefix
      a1 = fmaf(e1[j], hv[j], a1);
      a2 = fmaf(e2[j], hv[j], a2);
      s1 += e1[j]; s2 += e2[j];
    }
  }
}

// -------------------------------------------------------------------------
extern "C" void kernel_launch(void* const* d_in, const int* in_sizes, int n_in,
                              void* d_out, int out_size, void* d_ws, size_t ws_size,
                              hipStream_t stream)
{
  const float* h     = (const float*)d_in[0];
  const float* w     = (const float*)d_in[1];
  const float* a_src = (const float*)d_in[2];
  const float* a_dst = (const float*)d_in[3];
  const float* bias  = (const float*)d_in[4];
  float* out = (float*)d_out;

  float* p = (float*)d_ws;
  float* hp     = p; p += (size_t)H * B * F;        // 8.4 MB
  float* s      = p; p += H * B;
  float* dd     = p; p += H * B;
  float* vsort  = p; p += (size_t)H * M2;
  int*   gsort  = (int*)p; p += (size_t)H * M2;
  float* vs2    = p; p += (size_t)H * M2;
  int*   gs2    = (int*)p; p += (size_t)H * M2;
  float* TS     = p; p += (size_t)H * NTL2 * PELD;  // 2.2 MB
  float* totals = p; p += H * PELD;
  int* bstart   = (int*)p; p += H * (NB + 1);
  int* gcur     = (int*)p; p += H * NB;

  size_t need = (size_t)((char*)p - (char*)d_ws);
  if (ws_size < need) {
    fprintf(stderr, "kernel_launch: ws_size %zu < needed %zu\n", ws_size, need);
    return;
  }

  k_hprime<<<dim3(B / 64, H), 256, 0, stream>>>(h, w, a_src, a_dst, hp, s, dd);
  k_hist_scan<<<H, 1024, 0, stream>>>(s, dd, bstart, gcur);
  k_scatter<<<dim3(M2 / 512, H), 512, 0, stream>>>(s, dd, gcur, vsort, gsort);
  k_sort<<<dim3(NB / 4, H), 256, 0, stream>>>(vsort, gsort, bstart, vs2, gs2);
  k_peA<<<dim3(NTL2 / 4, H), 256, 0, stream>>>(vs2, gs2, hp, TS);
  k_peB<<<dim3(130, H), 64, 0, stream>>>(TS, totals);
  k_peC_out<<<dim3(NTL2 / 4, H), 256, 0, stream>>>(vs2, gs2, hp, TS, totals, bias, out);
}